// Round 8
// baseline (92.824 us; speedup 1.0000x reference)
//
#include <hip/hip_runtime.h>
#include <stdint.h>

#define NR 16384
#define KI 256
#define MO 128
#define ALPHA 0.01f
#define CH 32             // rows per chunk
#define NCH (NR / CH)     // 512 chunks
#define RB 8              // i-keys per thread in k_rank
#define JT 256            // j-keys staged in LDS per block
#define NJ (NR / JT)      // 64 j-chunks

typedef unsigned long long u64;

// sortable key: monotone float order, index tie-break (rank is a bijection)
static __device__ __forceinline__ u64 sort_key(float f, int j) {
    unsigned u = __float_as_uint(f);
    u ^= ((unsigned)((int)u >> 31)) | 0x80000000u;
    return (((u64)u) << 14) | (unsigned)(j & 0x3FFF);
}

// ---------------- K1: h = x@W^T (64x128 tile, 256 thr, 4x8 micro; R3-proven) + fused s1,s2,keys ----------------
__global__ __launch_bounds__(256) void k_gemm_fused(const float* __restrict__ x,
                                                    const float* __restrict__ w,
                                                    const float* __restrict__ a1,
                                                    const float* __restrict__ a2,
                                                    float* __restrict__ h,
                                                    float* __restrict__ s1,
                                                    float* __restrict__ s2,
                                                    u64* __restrict__ keys) {
    __shared__ float As[16][68];
    __shared__ float Bs[16][132];
    const int t = threadIdx.x;
    const int rowBase = blockIdx.x * 64;
    const int tx = t & 15;
    const int ty = t >> 4;
    const int ar = t >> 2, ak = (t & 3) << 2;
    const int br = t >> 1, bk = (t & 1) << 3;
    float acc[4][8] = {};
    for (int k0 = 0; k0 < KI; k0 += 16) {
        float4 av  = *(const float4*)&x[(rowBase + ar) * KI + k0 + ak];
        float4 bv0 = *(const float4*)&w[br * KI + k0 + bk];
        float4 bv1 = *(const float4*)&w[br * KI + k0 + bk + 4];
        __syncthreads();
        As[ak + 0][ar] = av.x; As[ak + 1][ar] = av.y;
        As[ak + 2][ar] = av.z; As[ak + 3][ar] = av.w;
        Bs[bk + 0][br] = bv0.x; Bs[bk + 1][br] = bv0.y;
        Bs[bk + 2][br] = bv0.z; Bs[bk + 3][br] = bv0.w;
        Bs[bk + 4][br] = bv1.x; Bs[bk + 5][br] = bv1.y;
        Bs[bk + 6][br] = bv1.z; Bs[bk + 7][br] = bv1.w;
        __syncthreads();
#pragma unroll
        for (int k = 0; k < 16; ++k) {
            float4 a4 = *(const float4*)&As[k][ty << 2];
            float4 b0 = *(const float4*)&Bs[k][tx << 3];
            float4 b1 = *(const float4*)&Bs[k][(tx << 3) + 4];
            float a[4] = {a4.x, a4.y, a4.z, a4.w};
            float b[8] = {b0.x, b0.y, b0.z, b0.w, b1.x, b1.y, b1.z, b1.w};
#pragma unroll
            for (int i = 0; i < 4; ++i)
#pragma unroll
                for (int j = 0; j < 8; ++j)
                    acc[i][j] = fmaf(a[i], b[j], acc[i][j]);
        }
    }
#pragma unroll
    for (int i = 0; i < 4; ++i) {
        float4 st0 = {acc[i][0], acc[i][1], acc[i][2], acc[i][3]};
        float4 st1 = {acc[i][4], acc[i][5], acc[i][6], acc[i][7]};
        float* hp = &h[(size_t)(rowBase + (ty << 2) + i) * MO + (tx << 3)];
        *(float4*)hp = st0;
        *(float4*)(hp + 4) = st1;
    }
    float4 a1lo = *(const float4*)&a1[tx << 3];
    float4 a1hi = *(const float4*)&a1[(tx << 3) + 4];
    float4 a2lo = *(const float4*)&a2[tx << 3];
    float4 a2hi = *(const float4*)&a2[(tx << 3) + 4];
    float a1v[8] = {a1lo.x, a1lo.y, a1lo.z, a1lo.w, a1hi.x, a1hi.y, a1hi.z, a1hi.w};
    float a2v[8] = {a2lo.x, a2lo.y, a2lo.z, a2lo.w, a2hi.x, a2hi.y, a2hi.z, a2hi.w};
#pragma unroll
    for (int r = 0; r < 4; ++r) {
        float p1 = 0.f, p2 = 0.f;
#pragma unroll
        for (int c = 0; c < 8; ++c) {
            p1 = fmaf(acc[r][c], a1v[c], p1);
            p2 = fmaf(acc[r][c], a2v[c], p2);
        }
#pragma unroll
        for (int off = 8; off; off >>= 1) {
            p1 += __shfl_xor(p1, off, 64);
            p2 += __shfl_xor(p2, off, 64);
        }
        if (tx == 0) {
            int row = rowBase + (ty << 2) + r;
            s1[row] = p1;
            s2[row] = p2;
            keys[row] = sort_key(p1, row);
        }
    }
}

// ---------------- K2: rank partials — LDS-broadcast j-keys, 8 i-keys/thread (R3-proven) ----------------
__global__ __launch_bounds__(256) void k_rank(const u64* __restrict__ keys,
                                              int* __restrict__ rankPart) {
    __shared__ u64 sk[JT];
    const int t = threadIdx.x;
    const int ibase = blockIdx.x * (256 * RB);
    const int jbase = blockIdx.y * JT;
    sk[t] = keys[jbase + t];
    u64 ki[RB];
#pragma unroll
    for (int k = 0; k < RB; ++k) ki[k] = keys[ibase + k * 256 + t];
    int cnt[RB] = {};
    __syncthreads();
#pragma unroll 4
    for (int jj = 0; jj < JT; ++jj) {
        u64 kj = sk[jj];                 // uniform addr -> LDS broadcast, conflict-free
#pragma unroll
        for (int k = 0; k < RB; ++k)
            cnt[k] += (kj < ki[k]) ? 1 : 0;
    }
#pragma unroll
    for (int k = 0; k < RB; ++k)
        rankPart[blockIdx.y * NR + ibase + k * 256 + t] = cnt[k];
}

// ---------------- K3: sum partials, scatter into sorted order (R3-proven) ----------------
__global__ __launch_bounds__(256) void k_scatter(const float* __restrict__ s1,
                                                 const int* __restrict__ rankPart,
                                                 float* __restrict__ s1s,
                                                 int* __restrict__ perm) {
    int i = blockIdx.x * 256 + threadIdx.x;
    int r = 0;
#pragma unroll
    for (int p = 0; p < NJ; ++p) r += rankPart[p * NR + i];
    s1s[r] = s1[i];
    perm[r] = i;
}

// ---------------- K4: per-chunk partial sums, 256-thr split-half ----------------
__global__ __launch_bounds__(256) void k_psum(const float* __restrict__ h,
                                              const int* __restrict__ perm,
                                              const float* __restrict__ s1s,
                                              float* __restrict__ psumH,
                                              float* __restrict__ psumSH) {
    __shared__ int pi[CH];
    __shared__ float ss[CH];
    __shared__ float rH[128], rS[128];
    const int t = threadIdx.x, c = t & 127, g = t >> 7, q = blockIdx.x;
    if (t < CH) { pi[t] = perm[q * CH + t]; ss[t] = s1s[q * CH + t]; }
    __syncthreads();
    float pH = 0.f, pS = 0.f;
#pragma unroll
    for (int m = 0; m < 16; ++m) {
        int row = g * 16 + m;
        float v = h[(size_t)pi[row] * MO + c];
        pH += v;
        pS = fmaf(ss[row], v, pS);
    }
    if (g == 1) { rH[c] = pH; rS[c] = pS; }
    __syncthreads();
    if (g == 0) {
        psumH[q * MO + c]  = pH + rH[c];
        psumSH[q * MO + c] = pS + rS[c];
    }
}

// ---------------- K5: exclusive suffix scan over 512 chunk sums (block per column; R3-proven) ----------------
__global__ __launch_bounds__(512) void k_scan(const float* __restrict__ psumH,
                                              const float* __restrict__ psumSH,
                                              float* __restrict__ cSufH,
                                              float* __restrict__ cSufS) {
    __shared__ float bufH[NCH], bufS[NCH];
    const int c = blockIdx.x, q = threadIdx.x;
    float vh = psumH[q * MO + c], vs = psumSH[q * MO + c];
    bufH[q] = vh; bufS[q] = vs;
    __syncthreads();
#pragma unroll
    for (int off = 1; off < NCH; off <<= 1) {
        float ah = 0.f, as = 0.f;
        if (q + off < NCH) { ah = bufH[q + off]; as = bufS[q + off]; }
        __syncthreads();
        bufH[q] += ah; bufS[q] += as;
        __syncthreads();
    }
    cSufH[q * MO + c] = bufH[q] - vh;   // exclusive suffix (chunks > q)
    cSufS[q * MO + c] = bufS[q] - vs;
}

// ---------------- K6: suffix arrays SHS[k]=(SH,SSH), 256-thr split-half ----------------
__global__ __launch_bounds__(256) void k_suffix(const float* __restrict__ h,
                                                const int* __restrict__ perm,
                                                const float* __restrict__ s1s,
                                                const float* __restrict__ cSufH,
                                                const float* __restrict__ cSufS,
                                                float2* __restrict__ SHS) {
    __shared__ int pi[CH];
    __shared__ float ss[CH];
    __shared__ float rH[128], rS[128];
    const int t = threadIdx.x, c = t & 127, g = t >> 7, q = blockIdx.x;
    if (t < CH) { pi[t] = perm[q * CH + t]; ss[t] = s1s[q * CH + t]; }
    __syncthreads();
    float v[16];
#pragma unroll
    for (int m = 0; m < 16; ++m)
        v[m] = h[(size_t)pi[g * 16 + m] * MO + c];
    if (g == 1) {
        float runH = cSufH[q * MO + c], runS = cSufS[q * MO + c];
#pragma unroll
        for (int m = 15; m >= 0; --m) {
            runH += v[m];
            runS = fmaf(ss[16 + m], v[m], runS);
            SHS[(size_t)(q * CH + 16 + m) * MO + c] = make_float2(runH, runS);
        }
        rH[c] = runH; rS[c] = runS;
    }
    __syncthreads();
    if (g == 0) {
        float runH = rH[c], runS = rS[c];
#pragma unroll
        for (int m = 15; m >= 0; --m) {
            runH += v[m];
            runS = fmaf(ss[m], v[m], runS);
            SHS[(size_t)(q * CH + m) * MO + c] = make_float2(runH, runS);
        }
    }
    if (q == NCH - 1 && t < 128) SHS[(size_t)NR * MO + t] = make_float2(0.f, 0.f);
}

// ---------------- K7: out[i][c], binary search fused (2 rows per block) ----------------
__global__ __launch_bounds__(256) void k_final(const float2* __restrict__ SHS,
                                               const float* __restrict__ s1s,
                                               const float* __restrict__ s2,
                                               float* __restrict__ out) {
    const int t = threadIdx.x;
    const int i = blockIdx.x * 2 + (t >> 7);
    const int c = t & 127;
    float s2v = s2[i];
    float tv = -s2v;
    int lo = 0, hi = NR;
    while (lo < hi) {                 // uniform per half-block; s1s is 64 KB L2-hot
        int mid = (lo + hi) >> 1;
        if (s1s[mid] < tv) lo = mid + 1; else hi = mid;
    }
    float2 tot = SHS[c];              // suffix from row 0 = totals
    float2 sv  = SHS[(size_t)lo * MO + c];
    out[(size_t)i * MO + c] = ALPHA * fmaf(s2v, tot.x, tot.y)
                            + (1.f - ALPHA) * fmaf(s2v, sv.x, sv.y);
}

extern "C" void kernel_launch(void* const* d_in, const int* in_sizes, int n_in,
                              void* d_out, int out_size, void* d_ws, size_t ws_size,
                              hipStream_t stream) {
    const float* x  = (const float*)d_in[0];
    const float* w  = (const float*)d_in[1];
    const float* a1 = (const float*)d_in[2];
    const float* a2 = (const float*)d_in[3];
    float* out = (float*)d_out;

    float*  ws     = (float*)d_ws;
    float*  h      = ws;                                // NR*MO
    float2* SHS    = (float2*)(h + (size_t)NR * MO);    // (NR+1)*MO float2
    float*  s1     = (float*)(SHS + (size_t)(NR + 1) * MO);
    float*  s2     = s1 + NR;
    float*  s1s    = s2 + NR;
    u64*    keys   = (u64*)(s1s + NR);                  // NR u64
    int*    perm   = (int*)(keys + NR);
    float*  psumH  = (float*)(perm + NR);               // NCH*MO
    float*  psumSH = psumH + NCH * MO;                  // NCH*MO
    float*  cSufH  = psumSH + NCH * MO;                 // NCH*MO
    float*  cSufS  = cSufH + NCH * MO;                  // NCH*MO
    // rankPart (NJ*NR ints = 4 MB) aliases SHS (16.8 MB); dead before SHS written in k_suffix
    int*    rankPart = (int*)SHS;

    k_gemm_fused<<<NR / 64, 256, 0, stream>>>(x, w, a1, a2, h, s1, s2, keys);
    k_rank<<<dim3(NR / (256 * RB), NJ), 256, 0, stream>>>(keys, rankPart);
    k_scatter<<<NR / 256, 256, 0, stream>>>(s1, rankPart, s1s, perm);
    k_psum<<<NCH, 256, 0, stream>>>(h, perm, s1s, psumH, psumSH);
    k_scan<<<MO, NCH, 0, stream>>>(psumH, psumSH, cSufH, cSufS);
    k_suffix<<<NCH, 256, 0, stream>>>(h, perm, s1s, cSufH, cSufS, SHS);
    k_final<<<NR / 2, 256, 0, stream>>>(SHS, s1s, s2, out);
}

// Round 9
// 76.443 us; speedup vs baseline: 1.2143x; 1.2143x over previous
//
#include <hip/hip_runtime.h>
#include <stdint.h>

#define NR 16384
#define KI 256
#define MO 128
#define ALPHA 0.01f
#define CH 32             // rows per chunk
#define NCH (NR / CH)     // 512 chunks
#define RB 8              // i-keys per thread in k_rank
#define JT 256            // j-keys staged in LDS per block
#define NJ (NR / JT)      // 64 j-chunks

typedef unsigned long long u64;

// sortable key: monotone float order, index tie-break (rank is a bijection)
static __device__ __forceinline__ u64 sort_key(float f, int j) {
    unsigned u = __float_as_uint(f);
    u ^= ((unsigned)((int)u >> 31)) | 0x80000000u;
    return (((u64)u) << 14) | (unsigned)(j & 0x3FFF);
}

// ---------------- K1: h = x@W^T (64x128 tile, 256 thr, 4x8 micro; R3-proven) + fused s1,s2,keys, rank=0 ----------------
__global__ __launch_bounds__(256) void k_gemm_fused(const float* __restrict__ x,
                                                    const float* __restrict__ w,
                                                    const float* __restrict__ a1,
                                                    const float* __restrict__ a2,
                                                    float* __restrict__ h,
                                                    float* __restrict__ s1,
                                                    float* __restrict__ s2,
                                                    u64* __restrict__ keys,
                                                    int* __restrict__ rank) {
    __shared__ float As[16][68];
    __shared__ float Bs[16][132];
    const int t = threadIdx.x;
    const int rowBase = blockIdx.x * 64;
    const int tx = t & 15;
    const int ty = t >> 4;
    const int ar = t >> 2, ak = (t & 3) << 2;
    const int br = t >> 1, bk = (t & 1) << 3;
    float acc[4][8] = {};
    for (int k0 = 0; k0 < KI; k0 += 16) {
        float4 av  = *(const float4*)&x[(rowBase + ar) * KI + k0 + ak];
        float4 bv0 = *(const float4*)&w[br * KI + k0 + bk];
        float4 bv1 = *(const float4*)&w[br * KI + k0 + bk + 4];
        __syncthreads();
        As[ak + 0][ar] = av.x; As[ak + 1][ar] = av.y;
        As[ak + 2][ar] = av.z; As[ak + 3][ar] = av.w;
        Bs[bk + 0][br] = bv0.x; Bs[bk + 1][br] = bv0.y;
        Bs[bk + 2][br] = bv0.z; Bs[bk + 3][br] = bv0.w;
        Bs[bk + 4][br] = bv1.x; Bs[bk + 5][br] = bv1.y;
        Bs[bk + 6][br] = bv1.z; Bs[bk + 7][br] = bv1.w;
        __syncthreads();
#pragma unroll
        for (int k = 0; k < 16; ++k) {
            float4 a4 = *(const float4*)&As[k][ty << 2];
            float4 b0 = *(const float4*)&Bs[k][tx << 3];
            float4 b1 = *(const float4*)&Bs[k][(tx << 3) + 4];
            float a[4] = {a4.x, a4.y, a4.z, a4.w};
            float b[8] = {b0.x, b0.y, b0.z, b0.w, b1.x, b1.y, b1.z, b1.w};
#pragma unroll
            for (int i = 0; i < 4; ++i)
#pragma unroll
                for (int j = 0; j < 8; ++j)
                    acc[i][j] = fmaf(a[i], b[j], acc[i][j]);
        }
    }
#pragma unroll
    for (int i = 0; i < 4; ++i) {
        float4 st0 = {acc[i][0], acc[i][1], acc[i][2], acc[i][3]};
        float4 st1 = {acc[i][4], acc[i][5], acc[i][6], acc[i][7]};
        float* hp = &h[(size_t)(rowBase + (ty << 2) + i) * MO + (tx << 3)];
        *(float4*)hp = st0;
        *(float4*)(hp + 4) = st1;
    }
    float4 a1lo = *(const float4*)&a1[tx << 3];
    float4 a1hi = *(const float4*)&a1[(tx << 3) + 4];
    float4 a2lo = *(const float4*)&a2[tx << 3];
    float4 a2hi = *(const float4*)&a2[(tx << 3) + 4];
    float a1v[8] = {a1lo.x, a1lo.y, a1lo.z, a1lo.w, a1hi.x, a1hi.y, a1hi.z, a1hi.w};
    float a2v[8] = {a2lo.x, a2lo.y, a2lo.z, a2lo.w, a2hi.x, a2hi.y, a2hi.z, a2hi.w};
#pragma unroll
    for (int r = 0; r < 4; ++r) {
        float p1 = 0.f, p2 = 0.f;
#pragma unroll
        for (int c = 0; c < 8; ++c) {
            p1 = fmaf(acc[r][c], a1v[c], p1);
            p2 = fmaf(acc[r][c], a2v[c], p2);
        }
#pragma unroll
        for (int off = 8; off; off >>= 1) {
            p1 += __shfl_xor(p1, off, 64);
            p2 += __shfl_xor(p2, off, 64);
        }
        if (tx == 0) {
            int row = rowBase + (ty << 2) + r;
            s1[row] = p1;
            s2[row] = p2;
            keys[row] = sort_key(p1, row);
            rank[row] = 0;
        }
    }
}

// ---------------- K2: rank counts — LDS-broadcast j-keys, 8 i-keys/thread, int atomicAdd ----------------
__global__ __launch_bounds__(256) void k_rank(const u64* __restrict__ keys,
                                              int* __restrict__ rank) {
    __shared__ u64 sk[JT];
    const int t = threadIdx.x;
    const int ibase = blockIdx.x * (256 * RB);
    const int jbase = blockIdx.y * JT;
    sk[t] = keys[jbase + t];
    u64 ki[RB];
#pragma unroll
    for (int k = 0; k < RB; ++k) ki[k] = keys[ibase + k * 256 + t];
    int cnt[RB] = {};
    __syncthreads();
#pragma unroll 4
    for (int jj = 0; jj < JT; ++jj) {
        u64 kj = sk[jj];                 // uniform addr -> LDS broadcast, conflict-free
#pragma unroll
        for (int k = 0; k < RB; ++k)
            cnt[k] += (kj < ki[k]) ? 1 : 0;
    }
#pragma unroll
    for (int k = 0; k < RB; ++k)
        atomicAdd(&rank[ibase + k * 256 + t], cnt[k]);   // int: deterministic
}

// ---------------- K3: scatter into sorted order ----------------
__global__ __launch_bounds__(256) void k_scatter(const float* __restrict__ s1,
                                                 const int* __restrict__ rank,
                                                 float* __restrict__ s1s,
                                                 int* __restrict__ perm) {
    int i = blockIdx.x * 256 + threadIdx.x;
    int r = rank[i];
    s1s[r] = s1[i];
    perm[r] = i;
}

// ---------------- K4: within-chunk suffix (psum+suffix merged) + kidx searches on idle half-wave ----------------
__global__ __launch_bounds__(256) void k_chunk(const float* __restrict__ h,
                                               const int* __restrict__ perm,
                                               const float* __restrict__ s1s,
                                               const float* __restrict__ s2,
                                               float2* __restrict__ SHSw,
                                               int* __restrict__ kidx) {
    __shared__ int pi[CH];
    __shared__ float ss[CH];
    __shared__ float rH[128], rS[128];
    const int t = threadIdx.x, c = t & 127, g = t >> 7, q = blockIdx.x;
    if (t < CH) { pi[t] = perm[q * CH + t]; ss[t] = s1s[q * CH + t]; }
    __syncthreads();
    float v[16];
#pragma unroll
    for (int m = 0; m < 16; ++m)
        v[m] = h[(size_t)pi[g * 16 + m] * MO + c];
    if (g == 1) {
        float runH = 0.f, runS = 0.f;
#pragma unroll
        for (int m = 15; m >= 0; --m) {     // global rows 16..31, inclusive suffix
            runH += v[m];
            runS = fmaf(ss[16 + m], v[m], runS);
            SHSw[(size_t)(q * CH + 16 + m) * MO + c] = make_float2(runH, runS);
        }
        rH[c] = runH; rS[c] = runS;
    } else if (t < CH) {
        // kidx binary search for this chunk's 32 i's, hidden under g1's chain
        int i = q * CH + t;
        float tv = -s2[i];
        int lo = 0, hi = NR;
        while (lo < hi) {
            int mid = (lo + hi) >> 1;
            if (s1s[mid] < tv) lo = mid + 1; else hi = mid;
        }
        kidx[i] = lo;
    }
    __syncthreads();
    if (g == 0) {
        float runH = rH[c], runS = rS[c];
#pragma unroll
        for (int m = 15; m >= 0; --m) {     // global rows 0..15
            runH += v[m];
            runS = fmaf(ss[m], v[m], runS);
            SHSw[(size_t)(q * CH + m) * MO + c] = make_float2(runH, runS);
        }
    }
    if (q == NCH - 1 && t < 128) SHSw[(size_t)NR * MO + t] = make_float2(0.f, 0.f);
}

// ---------------- K5: exclusive suffix over chunk sums (= SHSw at chunk heads) ----------------
__global__ __launch_bounds__(512) void k_scan(const float2* __restrict__ SHSw,
                                              float2* __restrict__ cSuf) {
    __shared__ float bufH[NCH], bufS[NCH];
    const int c = blockIdx.x, q = threadIdx.x;
    float2 hs = SHSw[(size_t)(q * CH) * MO + c];   // inclusive suffix at chunk head = chunk sum
    bufH[q] = hs.x; bufS[q] = hs.y;
    __syncthreads();
#pragma unroll
    for (int off = 1; off < NCH; off <<= 1) {
        float ah = 0.f, as = 0.f;
        if (q + off < NCH) { ah = bufH[q + off]; as = bufS[q + off]; }
        __syncthreads();
        bufH[q] += ah; bufS[q] += as;
        __syncthreads();
    }
    cSuf[q * MO + c] = make_float2(bufH[q] - hs.x, bufS[q] - hs.y);   // chunks > q
    if (q == 0) cSuf[(size_t)NCH * MO + c] = make_float2(0.f, 0.f);
}

// ---------------- K6: out[i][c] = a*(s2*TH+TSH) + (1-a)*(s2*SH+SSH), SH = SHSw[k]+cSuf[k>>5] ----------------
__global__ __launch_bounds__(256) void k_final(const float2* __restrict__ SHSw,
                                               const float2* __restrict__ cSuf,
                                               const float* __restrict__ s2,
                                               const int* __restrict__ kidx,
                                               float* __restrict__ out) {
    int idx = blockIdx.x * 256 + threadIdx.x;
    int i = idx >> 7, c = idx & 127;
    float s2v = s2[i];
    int k = kidx[i];
    float2 w0 = SHSw[c];                            // within-chunk suffix at row 0
    float2 c0 = cSuf[c];                            // cSuf[chunk 0]
    float2 wk = SHSw[(size_t)k * MO + c];
    float2 ck = cSuf[(size_t)(k >> 5) * MO + c];    // CH = 32
    float th = w0.x + c0.x, tsh = w0.y + c0.y;      // totals
    float sh = wk.x + ck.x, sshv = wk.y + ck.y;
    out[idx] = ALPHA * fmaf(s2v, th, tsh) + (1.f - ALPHA) * fmaf(s2v, sh, sshv);
}

extern "C" void kernel_launch(void* const* d_in, const int* in_sizes, int n_in,
                              void* d_out, int out_size, void* d_ws, size_t ws_size,
                              hipStream_t stream) {
    const float* x  = (const float*)d_in[0];
    const float* w  = (const float*)d_in[1];
    const float* a1 = (const float*)d_in[2];
    const float* a2 = (const float*)d_in[3];
    float* out = (float*)d_out;

    float*  ws   = (float*)d_ws;
    float*  h    = ws;                                   // NR*MO floats
    float2* SHSw = (float2*)(h + (size_t)NR * MO);       // (NR+1)*MO float2
    float2* cSuf = SHSw + (size_t)(NR + 1) * MO;         // (NCH+1)*MO float2
    float*  s1   = (float*)(cSuf + (size_t)(NCH + 1) * MO);
    float*  s2   = s1 + NR;
    float*  s1s  = s2 + NR;
    u64*    keys = (u64*)(s1s + NR);                     // NR u64
    int*    perm = (int*)(keys + NR);
    int*    kidx = perm + NR;
    int*    rank = kidx + NR;

    k_gemm_fused<<<NR / 64, 256, 0, stream>>>(x, w, a1, a2, h, s1, s2, keys, rank);
    k_rank<<<dim3(NR / (256 * RB), NJ), 256, 0, stream>>>(keys, rank);
    k_scatter<<<NR / 256, 256, 0, stream>>>(s1, rank, s1s, perm);
    k_chunk<<<NCH, 256, 0, stream>>>(h, perm, s1s, s2, SHSw, kidx);
    k_scan<<<MO, NCH, 0, stream>>>(SHSw, cSuf);
    k_final<<<(NR * MO) / 256, 256, 0, stream>>>(SHSw, cSuf, s2, kidx, out);
}

// Round 10
// 60.757 us; speedup vs baseline: 1.5278x; 1.2582x over previous
//
#include <hip/hip_runtime.h>
#include <hip/hip_bf16.h>
#include <stdint.h>

#define NR 16384
#define KI 256
#define MO 128
#define ALPHA 0.01f
#define CH 32             // rows per chunk
#define NCH (NR / CH)     // 512 chunks
#define RB 8              // i-keys per thread in k_rank
#define JT 256            // j-keys staged in LDS per block
#define NJ (NR / JT)      // 64 j-chunks

typedef unsigned long long u64;
typedef __attribute__((ext_vector_type(8))) short bf16x8;
typedef __attribute__((ext_vector_type(4))) float f32x4;

// sortable key: monotone float order, index tie-break (rank is a bijection)
static __device__ __forceinline__ u64 sort_key(float f, int j) {
    unsigned u = __float_as_uint(f);
    u ^= ((unsigned)((int)u >> 31)) | 0x80000000u;
    return (((u64)u) << 14) | (unsigned)(j & 0x3FFF);
}

static __device__ __forceinline__ ushort2 cvt2(float a, float b) {
    __hip_bfloat162 r = __float22bfloat162_rn(make_float2(a, b));
    return *reinterpret_cast<ushort2*>(&r);
}

// ---------------- K1: h = x@W^T via bf16 MFMA (64x128 tile, 4 waves) + fused s1,s2,keys, rank=0 ----------------
__global__ __launch_bounds__(256) void k_gemm_fused(const float* __restrict__ x,
                                                    const float* __restrict__ w,
                                                    const float* __restrict__ a1,
                                                    const float* __restrict__ a2,
                                                    float* __restrict__ h,
                                                    float* __restrict__ s1,
                                                    float* __restrict__ s2,
                                                    u64* __restrict__ keys,
                                                    int* __restrict__ rank) {
    __shared__ ushort Abf[64][40];    // 64 rows x 32 k, +8 pad (80B stride: 16B-aligned, 2-way banks max)
    __shared__ ushort Bbf[128][40];   // 128 cols x 32 k
    const int t = threadIdx.x;
    const int lane = t & 63;
    const int wv = t >> 6;            // wave id 0..3 -> rows wv*16..wv*16+15
    const int rowBase = blockIdx.x * 64;
    const int xr = t >> 2, xc = (t & 3) << 3;   // x staging: row, col (8 floats)
    const int wr = t >> 1, wc = (t & 1) << 4;   // w staging: row, col (16 floats)
    const int fr = lane & 15;                   // A-row / B-col within tile
    const int fk = (lane >> 4) << 3;            // k offset of fragment

    f32x4 acc[8] = {};

    // prologue loads (ks = 0)
    float4 xv0 = *(const float4*)&x[(size_t)(rowBase + xr) * KI + xc];
    float4 xv1 = *(const float4*)&x[(size_t)(rowBase + xr) * KI + xc + 4];
    float4 wv0 = *(const float4*)&w[(size_t)wr * KI + wc];
    float4 wv1 = *(const float4*)&w[(size_t)wr * KI + wc + 4];
    float4 wv2 = *(const float4*)&w[(size_t)wr * KI + wc + 8];
    float4 wv3 = *(const float4*)&w[(size_t)wr * KI + wc + 12];

    for (int ks = 0; ks < KI / 32; ++ks) {
        __syncthreads();   // previous iteration's fragment reads complete
        {
            union { ushort2 u2[4]; bf16x8 v; } ap;
            ap.u2[0] = cvt2(xv0.x, xv0.y); ap.u2[1] = cvt2(xv0.z, xv0.w);
            ap.u2[2] = cvt2(xv1.x, xv1.y); ap.u2[3] = cvt2(xv1.z, xv1.w);
            *(bf16x8*)&Abf[xr][xc] = ap.v;
            union { ushort2 u2[4]; bf16x8 v; } bp0, bp1;
            bp0.u2[0] = cvt2(wv0.x, wv0.y); bp0.u2[1] = cvt2(wv0.z, wv0.w);
            bp0.u2[2] = cvt2(wv1.x, wv1.y); bp0.u2[3] = cvt2(wv1.z, wv1.w);
            bp1.u2[0] = cvt2(wv2.x, wv2.y); bp1.u2[1] = cvt2(wv2.z, wv2.w);
            bp1.u2[2] = cvt2(wv3.x, wv3.y); bp1.u2[3] = cvt2(wv3.z, wv3.w);
            *(bf16x8*)&Bbf[wr][wc] = bp0.v;
            *(bf16x8*)&Bbf[wr][wc + 8] = bp1.v;
        }
        __syncthreads();
        if (ks + 1 < KI / 32) {   // prefetch next K-step; overlaps fragment reads + MFMA
            int k0 = (ks + 1) * 32;
            xv0 = *(const float4*)&x[(size_t)(rowBase + xr) * KI + k0 + xc];
            xv1 = *(const float4*)&x[(size_t)(rowBase + xr) * KI + k0 + xc + 4];
            wv0 = *(const float4*)&w[(size_t)wr * KI + k0 + wc];
            wv1 = *(const float4*)&w[(size_t)wr * KI + k0 + wc + 4];
            wv2 = *(const float4*)&w[(size_t)wr * KI + k0 + wc + 8];
            wv3 = *(const float4*)&w[(size_t)wr * KI + k0 + wc + 12];
        }
        bf16x8 af = *(const bf16x8*)&Abf[wv * 16 + fr][fk];
#pragma unroll
        for (int n = 0; n < 8; ++n) {
            bf16x8 bfr = *(const bf16x8*)&Bbf[n * 16 + fr][fk];
            acc[n] = __builtin_amdgcn_mfma_f32_16x16x32_bf16(af, bfr, acc[n], 0, 0, 0);
        }
    }

    // epilogue: h write. C/D layout: col = lane&15, row = (lane>>4)*4 + reg  [m89-verified]
    const int rq = lane >> 4;   // quarter id
#pragma unroll
    for (int n = 0; n < 8; ++n)
#pragma unroll
        for (int r = 0; r < 4; ++r)
            h[(size_t)(rowBase + wv * 16 + rq * 4 + r) * MO + n * 16 + fr] = acc[n][r];

    // fused s1,s2,keys,rank=0
    float a1v[8], a2v[8];
#pragma unroll
    for (int n = 0; n < 8; ++n) { a1v[n] = a1[n * 16 + fr]; a2v[n] = a2[n * 16 + fr]; }
#pragma unroll
    for (int r = 0; r < 4; ++r) {
        float p1 = 0.f, p2 = 0.f;
#pragma unroll
        for (int n = 0; n < 8; ++n) {
            p1 = fmaf(acc[n][r], a1v[n], p1);
            p2 = fmaf(acc[n][r], a2v[n], p2);
        }
#pragma unroll
        for (int off = 8; off; off >>= 1) {   // reduce over fr (lane bits 0..3)
            p1 += __shfl_xor(p1, off, 64);
            p2 += __shfl_xor(p2, off, 64);
        }
        if (fr == 0) {
            int row = rowBase + wv * 16 + rq * 4 + r;
            s1[row] = p1;
            s2[row] = p2;
            keys[row] = sort_key(p1, row);
            rank[row] = 0;
        }
    }
}

// ---------------- K2: rank counts — LDS-broadcast j-keys, 8 i-keys/thread, int atomicAdd (R9-proven) ----------------
__global__ __launch_bounds__(256) void k_rank(const u64* __restrict__ keys,
                                              int* __restrict__ rank) {
    __shared__ u64 sk[JT];
    const int t = threadIdx.x;
    const int ibase = blockIdx.x * (256 * RB);
    const int jbase = blockIdx.y * JT;
    sk[t] = keys[jbase + t];
    u64 ki[RB];
#pragma unroll
    for (int k = 0; k < RB; ++k) ki[k] = keys[ibase + k * 256 + t];
    int cnt[RB] = {};
    __syncthreads();
#pragma unroll 4
    for (int jj = 0; jj < JT; ++jj) {
        u64 kj = sk[jj];                 // uniform addr -> LDS broadcast, conflict-free
#pragma unroll
        for (int k = 0; k < RB; ++k)
            cnt[k] += (kj < ki[k]) ? 1 : 0;
    }
#pragma unroll
    for (int k = 0; k < RB; ++k)
        atomicAdd(&rank[ibase + k * 256 + t], cnt[k]);   // int: deterministic
}

// ---------------- K3: scatter into sorted order (R9-proven) ----------------
__global__ __launch_bounds__(256) void k_scatter(const float* __restrict__ s1,
                                                 const int* __restrict__ rank,
                                                 float* __restrict__ s1s,
                                                 int* __restrict__ perm) {
    int i = blockIdx.x * 256 + threadIdx.x;
    int r = rank[i];
    s1s[r] = s1[i];
    perm[r] = i;
}

// ---------------- K4: within-chunk suffix + kidx searches on idle half-wave (R9-proven) ----------------
__global__ __launch_bounds__(256) void k_chunk(const float* __restrict__ h,
                                               const int* __restrict__ perm,
                                               const float* __restrict__ s1s,
                                               const float* __restrict__ s2,
                                               float2* __restrict__ SHSw,
                                               int* __restrict__ kidx) {
    __shared__ int pi[CH];
    __shared__ float ss[CH];
    __shared__ float rH[128], rS[128];
    const int t = threadIdx.x, c = t & 127, g = t >> 7, q = blockIdx.x;
    if (t < CH) { pi[t] = perm[q * CH + t]; ss[t] = s1s[q * CH + t]; }
    __syncthreads();
    float v[16];
#pragma unroll
    for (int m = 0; m < 16; ++m)
        v[m] = h[(size_t)pi[g * 16 + m] * MO + c];
    if (g == 1) {
        float runH = 0.f, runS = 0.f;
#pragma unroll
        for (int m = 15; m >= 0; --m) {     // global rows 16..31, inclusive suffix
            runH += v[m];
            runS = fmaf(ss[16 + m], v[m], runS);
            SHSw[(size_t)(q * CH + 16 + m) * MO + c] = make_float2(runH, runS);
        }
        rH[c] = runH; rS[c] = runS;
    } else if (t < CH) {
        int i = q * CH + t;
        float tv = -s2[i];
        int lo = 0, hi = NR;
        while (lo < hi) {
            int mid = (lo + hi) >> 1;
            if (s1s[mid] < tv) lo = mid + 1; else hi = mid;
        }
        kidx[i] = lo;
    }
    __syncthreads();
    if (g == 0) {
        float runH = rH[c], runS = rS[c];
#pragma unroll
        for (int m = 15; m >= 0; --m) {     // global rows 0..15
            runH += v[m];
            runS = fmaf(ss[m], v[m], runS);
            SHSw[(size_t)(q * CH + m) * MO + c] = make_float2(runH, runS);
        }
    }
    if (q == NCH - 1 && t < 128) SHSw[(size_t)NR * MO + t] = make_float2(0.f, 0.f);
}

// ---------------- K5: exclusive suffix over chunk sums (= SHSw at chunk heads; R9-proven) ----------------
__global__ __launch_bounds__(512) void k_scan(const float2* __restrict__ SHSw,
                                              float2* __restrict__ cSuf) {
    __shared__ float bufH[NCH], bufS[NCH];
    const int c = blockIdx.x, q = threadIdx.x;
    float2 hs = SHSw[(size_t)(q * CH) * MO + c];   // inclusive suffix at chunk head = chunk sum
    bufH[q] = hs.x; bufS[q] = hs.y;
    __syncthreads();
#pragma unroll
    for (int off = 1; off < NCH; off <<= 1) {
        float ah = 0.f, as = 0.f;
        if (q + off < NCH) { ah = bufH[q + off]; as = bufS[q + off]; }
        __syncthreads();
        bufH[q] += ah; bufS[q] += as;
        __syncthreads();
    }
    cSuf[q * MO + c] = make_float2(bufH[q] - hs.x, bufS[q] - hs.y);   // chunks > q
    if (q == 0) cSuf[(size_t)NCH * MO + c] = make_float2(0.f, 0.f);
}

// ---------------- K6: out[i][c]; SH = SHSw[k]+cSuf[k>>5] (R9-proven) ----------------
__global__ __launch_bounds__(256) void k_final(const float2* __restrict__ SHSw,
                                               const float2* __restrict__ cSuf,
                                               const float* __restrict__ s2,
                                               const int* __restrict__ kidx,
                                               float* __restrict__ out) {
    int idx = blockIdx.x * 256 + threadIdx.x;
    int i = idx >> 7, c = idx & 127;
    float s2v = s2[i];
    int k = kidx[i];
    float2 w0 = SHSw[c];
    float2 c0 = cSuf[c];
    float2 wk = SHSw[(size_t)k * MO + c];
    float2 ck = cSuf[(size_t)(k >> 5) * MO + c];    // CH = 32
    float th = w0.x + c0.x, tsh = w0.y + c0.y;      // totals
    float sh = wk.x + ck.x, sshv = wk.y + ck.y;
    out[idx] = ALPHA * fmaf(s2v, th, tsh) + (1.f - ALPHA) * fmaf(s2v, sh, sshv);
}

extern "C" void kernel_launch(void* const* d_in, const int* in_sizes, int n_in,
                              void* d_out, int out_size, void* d_ws, size_t ws_size,
                              hipStream_t stream) {
    const float* x  = (const float*)d_in[0];
    const float* w  = (const float*)d_in[1];
    const float* a1 = (const float*)d_in[2];
    const float* a2 = (const float*)d_in[3];
    float* out = (float*)d_out;

    float*  ws   = (float*)d_ws;
    float*  h    = ws;                                   // NR*MO floats
    float2* SHSw = (float2*)(h + (size_t)NR * MO);       // (NR+1)*MO float2
    float2* cSuf = SHSw + (size_t)(NR + 1) * MO;         // (NCH+1)*MO float2
    float*  s1   = (float*)(cSuf + (size_t)(NCH + 1) * MO);
    float*  s2   = s1 + NR;
    float*  s1s  = s2 + NR;
    u64*    keys = (u64*)(s1s + NR);                     // NR u64
    int*    perm = (int*)(keys + NR);
    int*    kidx = perm + NR;
    int*    rank = kidx + NR;

    k_gemm_fused<<<NR / 64, 256, 0, stream>>>(x, w, a1, a2, h, s1, s2, keys, rank);
    k_rank<<<dim3(NR / (256 * RB), NJ), 256, 0, stream>>>(keys, rank);
    k_scatter<<<NR / 256, 256, 0, stream>>>(s1, rank, s1s, perm);
    k_chunk<<<NCH, 256, 0, stream>>>(h, perm, s1s, s2, SHSw, kidx);
    k_scan<<<MO, NCH, 0, stream>>>(SHSw, cSuf);
    k_final<<<(NR * MO) / 256, 256, 0, stream>>>(SHSw, cSuf, s2, kidx, out);
}